// Round 1
// baseline (272.237 us; speedup 1.0000x reference)
//
#include <hip/hip_runtime.h>

// Problem constants (from reference setup_inputs) — all tensors are float32.
#define B_DIM 2
#define C_DIM 64
#define N_DIM 1024
#define E_DIM 32
#define BE_DIM (B_DIM * E_DIM)   // 64
#define ITILE 16                 // rows of the N x N image per block

// ---------------------------------------------------------------------------
// Kernel 1: t[b,e,n] = sum_c th12[e,c] * emb[b,c,n], for both parameter sets.
// Grid: (N/256, BE), block 256. ~17 MFLOP total — negligible.
// ---------------------------------------------------------------------------
__global__ __launch_bounds__(256) void compute_t_kernel(
    const float* __restrict__ emb,
    const float* __restrict__ th12_1,
    const float* __restrict__ th12_2,
    float* __restrict__ t1,
    float* __restrict__ t2)
{
    const int n  = blockIdx.x * 256 + threadIdx.x;
    const int be = blockIdx.y;
    const int b  = be >> 5;       // E=32
    const int e  = be & 31;

    const float* __restrict__ embp = emb + (size_t)b * C_DIM * N_DIM + n;
    const float* __restrict__ w1   = th12_1 + e * C_DIM;
    const float* __restrict__ w2   = th12_2 + e * C_DIM;

    float acc1 = 0.f, acc2 = 0.f;
#pragma unroll
    for (int c = 0; c < C_DIM; ++c) {
        const float x = embp[(size_t)c * N_DIM];
        acc1 = fmaf(w1[c], x, acc1);
        acc2 = fmaf(w2[c], x, acc2);
    }
    t1[be * N_DIM + n] = acc1;
    t2[be * N_DIM + n] = acc2;
}

// ---------------------------------------------------------------------------
// Kernel 2: out[b,e,i,j] = relu(2*max(t1i,t1j) + th5_1[e]*(i==j))
//                        * sigmoid(relu(2*max(t2i,t2j) + th5_2[e]*(i==j)))
//
// Row-tiled: each block produces ITILE=16 consecutive rows i of one (b,e)
// image. Each lane owns 4 consecutive j, loads its t-row float4s ONCE and
// reuses them across all 16 rows from registers. Per-row t[i] scalars are
// wave-uniform (s_load). Grid: (N/ITILE, BE) = (64, 64) = 4096 blocks,
// 64 KB written per block -> dispatch overhead amortized 16x vs. 1-row
// blocks. 2*max(x,y) == max(2x,2y): the doubling is hoisted out of the
// inner loop (precomputed a2/g2 per lane, t?i2 per row).
// ---------------------------------------------------------------------------
__global__ __launch_bounds__(256) void edge_kernel(
    const float* __restrict__ t1,
    const float* __restrict__ t2,
    const float* __restrict__ th5_1,
    const float* __restrict__ th5_2,
    float* __restrict__ out)
{
    const int be = blockIdx.y;
    const int e  = be & (E_DIM - 1);
    const int i0 = blockIdx.x * ITILE;
    const int jb = threadIdx.x * 4;

    const float* __restrict__ t1r = t1 + be * N_DIM;
    const float* __restrict__ t2r = t2 + be * N_DIM;

    const float th51 = th5_1[e];
    const float th52 = th5_2[e];

    const float4 a = *reinterpret_cast<const float4*>(t1r + jb);
    const float4 g = *reinterpret_cast<const float4*>(t2r + jb);

    // 2*t1[j] / 2*t2[j], kept in registers for all 16 rows.
    const float a2[4] = {a.x + a.x, a.y + a.y, a.z + a.z, a.w + a.w};
    const float g2[4] = {g.x + g.x, g.y + g.y, g.z + g.z, g.w + g.w};

    float* dst = out + ((size_t)be * N_DIM + i0) * N_DIM + jb;

#pragma unroll
    for (int r = 0; r < ITILE; ++r) {
        const int i = i0 + r;
        const float t1i2 = 2.f * t1r[i];   // uniform address -> s_load
        const float t2i2 = 2.f * t2r[i];

        float4 o;
        float* op = reinterpret_cast<float*>(&o);
#pragma unroll
        for (int k = 0; k < 4; ++k) {
            float d1 = fmaxf(t1i2, a2[k]);     // == 2*max(t1i, t1j)
            float d2 = fmaxf(t2i2, g2[k]);
            if (i == jb + k) { d1 += th51; d2 += th52; }   // diagonal term
            const float adj  = fmaxf(d1, 0.f);
            const float rg   = fmaxf(d2, 0.f);
            const float gate = 1.f / (1.f + __expf(-rg));
            op[k] = adj * gate;
        }

        *reinterpret_cast<float4*>(dst + (size_t)r * N_DIM) = o;
    }
}

// ---------------------------------------------------------------------------
extern "C" void kernel_launch(void* const* d_in, const int* in_sizes, int n_in,
                              void* d_out, int out_size, void* d_ws, size_t ws_size,
                              hipStream_t stream) {
    const float* emb    = (const float*)d_in[0];
    const float* th12_1 = (const float*)d_in[1];
    // d_in[2] = th34_1 (unused by reference)
    const float* th5_1  = (const float*)d_in[3];
    const float* th12_2 = (const float*)d_in[4];
    // d_in[5] = th34_2 (unused by reference)
    const float* th5_2  = (const float*)d_in[6];
    float* out = (float*)d_out;

    float* t1 = (float*)d_ws;                       // BE*N floats = 256 KB
    float* t2 = t1 + (size_t)BE_DIM * N_DIM;        // another 256 KB

    dim3 g1(N_DIM / 256, BE_DIM);
    compute_t_kernel<<<g1, 256, 0, stream>>>(emb, th12_1, th12_2, t1, t2);

    dim3 g2(N_DIM / ITILE, BE_DIM);
    edge_kernel<<<g2, 256, 0, stream>>>(t1, t2, th5_1, th5_2, out);
}